// Round 7
// baseline (259.324 us; speedup 1.0000x reference)
//
#include <hip/hip_runtime.h>
#include <hip/hip_bf16.h>

// INPUTS/OUTPUT ARE FLOAT32 (R1/R3/R4 NaN'd reading them as bf16).
// PERF NOTES:
//  - R5: __launch_bounds__(256,4) -> VGPR 64, ~50 reg spills, FETCH 514 MB,
//    2.6x slower. Keep (256,2): VGPR 96, zero spills.
//  - R6: edge is trans-pipe bound (65 trans/m-step @ ~16cyc ≈ 1040 cyc of
//    1594). R7: batch rcp 4-way (32 rcp -> 8), clamps keep products finite.

#define NTOT 2048
#define MTOT 2048
#define MSPLIT 32
#define MCHUNK 64   // == per-block m range: single staging chunk

typedef short bf16x8 __attribute__((ext_vector_type(8)));
typedef float f32x4  __attribute__((ext_vector_type(4)));
typedef int   i32x4  __attribute__((ext_vector_type(4)));

// exp(x) = 2^(x*log2e); sigmoid(x) = 1/(1+2^(-x*log2e))
#define NL2E (-1.4426950408889634f)
// exp(-d2/5) = 2^(d2 * -log2e/5)
#define C1E  (-0.2885390081777927f)

__device__ __forceinline__ float fast_exp2(float x) {
#if __has_builtin(__builtin_amdgcn_exp2f)
  return __builtin_amdgcn_exp2f(x);
#else
  return __exp2f(x);
#endif
}
__device__ __forceinline__ float fast_rcp(float x) {
#if __has_builtin(__builtin_amdgcn_rcpf)
  return __builtin_amdgcn_rcpf(x);
#else
  return 1.0f / x;
#endif
}
__device__ __forceinline__ float fast_rsq(float x) {
#if __has_builtin(__builtin_amdgcn_rsqf)
  return __builtin_amdgcn_rsqf(x);
#else
  return rsqrtf(x);
#endif
}

// f32 -> bf16 raw bits, round-to-nearest-even (for MFMA B fragments)
__device__ __forceinline__ short to_bf16_rne(float x) {
  union { float f; unsigned u; } v; v.f = x;
  unsigned r = v.u + 0x7FFFu + ((v.u >> 16) & 1u);
  return (short)(r >> 16);
}

// pack two f32 -> two bf16 (round-half-up) in one u32 (lo in low half).
__device__ __forceinline__ unsigned pack_bf16_rn(float lo, float hi) {
  union { float f; unsigned u; } a, b;
  a.f = lo; b.f = hi;
  unsigned au = a.u + 0x8000u, bu = b.u + 0x8000u;
#if __has_builtin(__builtin_amdgcn_perm)
  return __builtin_amdgcn_perm(bu, au, 0x07060302u);
#else
  return (au >> 16) | (bu & 0xffff0000u);
#endif
}

// ---------------------------------------------------------------------------
// Edge phase: per wave, 16 n-rows; loop over this block's 64-m range.
// Grid: (NTOT/64) * MSPLIT = 1024 blocks of 256.
// ---------------------------------------------------------------------------
__global__ __launch_bounds__(256, 2)
void edge_kernel(const float* __restrict__ h_l,
                 const float* __restrict__ x_l,
                 const float* __restrict__ h_r,
                 const float* __restrict__ x_r,
                 const float* __restrict__ W1,
                 const float* __restrict__ b1,
                 const float* __restrict__ W2,
                 const float* __restrict__ b2,
                 float* __restrict__ num_g,
                 float* __restrict__ den_g) {
  __shared__ float hr_s[MCHUNK][64];  // h_r chunk (16 KB)
  __shared__ float xr_s[MCHUNK][8];   // x_r(3), r_p(3), pad (2 KB)

  const int tid  = threadIdx.x;
  const int wave = tid >> 6;
  const int lane = tid & 63;
  const int l15  = lane & 15;
  const int quad = lane >> 4;

  const int nblk   = blockIdx.x / MSPLIT;
  const int msplit = blockIdx.x % MSPLIT;
  const int n0     = nblk * 64 + wave * 16;
  const int mBase  = msplit * MCHUNK;

  // per-lane A-row n
  const int nA = n0 + l15;
  const float xl0 = x_l[nA * 3 + 0];
  const float xl1 = x_l[nA * 3 + 1];
  const float xl2 = x_l[nA * 3 + 2];
  const float lp0 = h_l[nA * 64 + 61];
  const float lp1 = h_l[nA * 64 + 62];
  const float lp2 = h_l[nA * 64 + 63];

  // layer-1 weights for this lane's 16 h1 columns (h1 = quad*8+j and 32+quad*8+j)
  float w1d[16], w1h[16], w1y[16], b1p[16];
#pragma unroll
  for (int j = 0; j < 8; ++j) {
    const int ha = quad * 8 + j, hb = 32 + quad * 8 + j;
    w1d[j] = W1[0 * 64 + ha];   w1d[8 + j] = W1[0 * 64 + hb];
    w1h[j] = W1[1 * 64 + ha];   w1h[8 + j] = W1[1 * 64 + hb];
    w1y[j] = W1[2 * 64 + ha];   w1y[8 + j] = W1[2 * 64 + hb];
    // edge_raw[3] == 1 -> fold W1 row 3 into bias
    b1p[j]     = b1[ha] + W1[3 * 64 + ha];
    b1p[8 + j] = b1[hb] + W1[3 * 64 + hb];
  }

  // W2 B-frags (bf16): B[k = half*32 + quad*8 + j][col = c*16 + l15]
  bf16x8 Bfrag[4][2];
#pragma unroll
  for (int c = 0; c < 4; ++c) {
#pragma unroll
    for (int h = 0; h < 2; ++h) {
      bf16x8 f;
#pragma unroll
      for (int j = 0; j < 8; ++j) {
        const int k = h * 32 + quad * 8 + j;
        f[j] = to_bf16_rne(W2[k * 64 + c * 16 + l15]);
      }
      Bfrag[c][h] = f;
    }
  }

  // b2 folded into sigmoid exp-arg: arg = e*NL2E + NL2E*b2[h2]
  float b2c[4];
#pragma unroll
  for (int c = 0; c < 4; ++c) b2c[c] = NL2E * b2[c * 16 + l15];

  // stage h_r chunk + x_r/r_p chunk
  for (int idx = tid; idx < MCHUNK * 64; idx += 256) {
    const int mm = idx >> 6, hh = idx & 63;
    hr_s[mm][hh] = h_r[(mBase + mm) * 64 + hh];
  }
  for (int idx = tid; idx < MCHUNK * 8; idx += 256) {
    const int mm = idx >> 3, k = idx & 7;
    float v = 0.f;
    const int m = mBase + mm;
    if (k < 3)      v = x_r[m * 3 + k];
    else if (k < 6) v = h_r[m * 64 + 61 + (k - 3)];
    xr_s[mm][k] = v;
  }

  const f32x4 zero4 = {0.f, 0.f, 0.f, 0.f};
  float numr[4][4], denr[4][4];
#pragma unroll
  for (int c = 0; c < 4; ++c)
#pragma unroll
    for (int r = 0; r < 4; ++r) { numr[c][r] = 0.f; denr[c][r] = 0.f; }

  __syncthreads();

#pragma unroll 1
  for (int ms = 0; ms < MCHUNK; ++ms) {
    // broadcast per-m values
    const float xr0 = xr_s[ms][0], xr1 = xr_s[ms][1], xr2 = xr_s[ms][2];
    const float rp0 = xr_s[ms][3], rp1 = xr_s[ms][4], rp2 = xr_s[ms][5];
    const float dx = xl0 - xr0, dy = xl1 - xr1, dz = xl2 - xr2;
    const float d2 = fmaf(dz, dz, fmaf(dy, dy, dx * dx));
    const float dist = fast_exp2(d2 * C1E);          // exp(-d2/5)
    const float hb = fmaf(lp1, rp0, lp0 * rp1);
    const float hy = lp2 * rp2;

    // layer 1, A-frag element order. Denominators d = 1 + exp(-t).
    // Clamp exp arg source: t >= -20 keeps d <= ~2^28.85 so 4-products < 2^128.
    float t[16], dd[16];
#pragma unroll
    for (int j = 0; j < 16; ++j) {
      const float tj = fmaf(dist, w1d[j], fmaf(hb, w1h[j], fmaf(hy, w1y[j], b1p[j])));
      t[j] = tj;
      dd[j] = 1.0f + fast_exp2(fmaxf(tj, -20.0f) * NL2E);
    }
    // silu(t) = t / d, divisions batched 4-way: one rcp per 4.
    float s[16];
#pragma unroll
    for (int g = 0; g < 4; ++g) {
      const int j0 = g * 4;
      const float p01 = dd[j0 + 0] * dd[j0 + 1];
      const float p23 = dd[j0 + 2] * dd[j0 + 3];
      const float r   = fast_rcp(p01 * p23);
      const float r01 = p23 * r;   // 1/(d0*d1)
      const float r23 = p01 * r;   // 1/(d2*d3)
      s[j0 + 0] = t[j0 + 0] * (dd[j0 + 1] * r01);
      s[j0 + 1] = t[j0 + 1] * (dd[j0 + 0] * r01);
      s[j0 + 2] = t[j0 + 2] * (dd[j0 + 3] * r23);
      s[j0 + 3] = t[j0 + 3] * (dd[j0 + 2] * r23);
    }
    i32x4 p0, p1;
    p0.x = pack_bf16_rn(s[0], s[1]);   p0.y = pack_bf16_rn(s[2], s[3]);
    p0.z = pack_bf16_rn(s[4], s[5]);   p0.w = pack_bf16_rn(s[6], s[7]);
    p1.x = pack_bf16_rn(s[8], s[9]);   p1.y = pack_bf16_rn(s[10], s[11]);
    p1.z = pack_bf16_rn(s[12], s[13]); p1.w = pack_bf16_rn(s[14], s[15]);
    const bf16x8 A0 = __builtin_bit_cast(bf16x8, p0);
    const bf16x8 A1 = __builtin_bit_cast(bf16x8, p1);

    f32x4 acc[4];
#pragma unroll
    for (int c = 0; c < 4; ++c) {
      acc[c] = __builtin_amdgcn_mfma_f32_16x16x32_bf16(A0, Bfrag[c][0], zero4, 0, 0, 0);
      acc[c] = __builtin_amdgcn_mfma_f32_16x16x32_bf16(A1, Bfrag[c][1], acc[c], 0, 0, 0);
    }

    // sigmoid w = 1/(1 + 2^arg), arg = acc*NL2E + b2c, clamped <= 28 so
    // 4-products stay < 2^128. One rcp per 4 (per c-group).
#pragma unroll
    for (int c = 0; c < 4; ++c) {
      const float hrv = hr_s[ms][c * 16 + l15];
      float sd[4];
#pragma unroll
      for (int r = 0; r < 4; ++r)
        sd[r] = 1.0f + fast_exp2(fminf(fmaf(acc[c][r], NL2E, b2c[c]), 28.0f));
      const float p01 = sd[0] * sd[1];
      const float p23 = sd[2] * sd[3];
      const float rr  = fast_rcp(p01 * p23);
      const float r01 = p23 * rr;
      const float r23 = p01 * rr;
      const float w0 = sd[1] * r01;
      const float w1 = sd[0] * r01;
      const float w2 = sd[3] * r23;
      const float w3 = sd[2] * r23;
      numr[c][0] = fmaf(w0, hrv, numr[c][0]);  denr[c][0] += w0;
      numr[c][1] = fmaf(w1, hrv, numr[c][1]);  denr[c][1] += w1;
      numr[c][2] = fmaf(w2, hrv, numr[c][2]);  denr[c][2] += w2;
      numr[c][3] = fmaf(w3, hrv, numr[c][3]);  denr[c][3] += w3;
    }
  }

#pragma unroll
  for (int c = 0; c < 4; ++c)
#pragma unroll
    for (int r = 0; r < 4; ++r) {
      const int n = n0 + quad * 4 + r;
      const int h2 = c * 16 + l15;
      atomicAdd(&num_g[n * 64 + h2], numr[c][r]);
      atomicAdd(&den_g[n * 64 + h2], denr[c][r]);
    }
}

// ---------------------------------------------------------------------------
// Node phase: one wave per row. h_agg = num/(den+1e-6); z = cat(h_l,h_agg)@Wn1
// + bn1 -> LN -> silu -> @Wn2 + bn2; out = h_l + z.
// ---------------------------------------------------------------------------
__global__ __launch_bounds__(256)
void node_kernel(const float* __restrict__ h_l,
                 const float* __restrict__ num_g,
                 const float* __restrict__ den_g,
                 const float* __restrict__ Wn1,
                 const float* __restrict__ bn1,
                 const float* __restrict__ ln_g,
                 const float* __restrict__ ln_b,
                 const float* __restrict__ Wn2,
                 const float* __restrict__ bn2,
                 float* __restrict__ out) {
  __shared__ float Wn1_s[128 * 64];
  __shared__ float Wn2_s[64 * 64];
  __shared__ float xbuf[4][128];
  __shared__ float zbuf[4][64];

  const int tid = threadIdx.x;
  for (int i = tid; i < 128 * 64; i += 256) Wn1_s[i] = Wn1[i];
  for (int i = tid; i < 64 * 64; i += 256) Wn2_s[i] = Wn2[i];

  const int wave = tid >> 6, lane = tid & 63;
  const int row = blockIdx.x * 4 + wave;

  const float hl = h_l[row * 64 + lane];
  const float dn = den_g[row * 64 + lane] + 1e-6f;
  const float hagg = num_g[row * 64 + lane] * fast_rcp(dn);
  xbuf[wave][lane] = hl;
  xbuf[wave][64 + lane] = hagg;
  __syncthreads();

  float t = bn1[lane];
#pragma unroll 8
  for (int k = 0; k < 128; ++k) t = fmaf(xbuf[wave][k], Wn1_s[k * 64 + lane], t);

  float s1 = t, s2 = t * t;
#pragma unroll
  for (int off = 32; off; off >>= 1) {
    s1 += __shfl_xor(s1, off);
    s2 += __shfl_xor(s2, off);
  }
  const float mu = s1 * 0.015625f;
  const float var = fmaf(s2, 0.015625f, -mu * mu);
  const float rs = fast_rsq(var + 1e-5f);
  const float zn = fmaf((t - mu) * rs, ln_g[lane], ln_b[lane]);
  const float sz = zn * fast_rcp(1.0f + fast_exp2(zn * NL2E));  // silu
  zbuf[wave][lane] = sz;
  __syncthreads();

  float o = bn2[lane];
#pragma unroll 8
  for (int k = 0; k < 64; ++k) o = fmaf(zbuf[wave][k], Wn2_s[k * 64 + lane], o);

  out[row * 64 + lane] = hl + o;
}

extern "C" void kernel_launch(void* const* d_in, const int* in_sizes, int n_in,
                              void* d_out, int out_size, void* d_ws, size_t ws_size,
                              hipStream_t stream) {
  const float* h_l = (const float*)d_in[0];
  const float* x_l = (const float*)d_in[1];
  const float* h_r = (const float*)d_in[2];
  const float* x_r = (const float*)d_in[3];
  const float* W1  = (const float*)d_in[4];
  const float* b1  = (const float*)d_in[5];
  const float* W2  = (const float*)d_in[6];
  const float* b2  = (const float*)d_in[7];
  const float* Wn1 = (const float*)d_in[8];
  const float* bn1 = (const float*)d_in[9];
  const float* lng = (const float*)d_in[10];
  const float* lnb = (const float*)d_in[11];
  const float* Wn2 = (const float*)d_in[12];
  const float* bn2 = (const float*)d_in[13];

  float* num_g = (float*)d_ws;
  float* den_g = num_g + (size_t)NTOT * 64;

  hipMemsetAsync(d_ws, 0, (size_t)NTOT * 64 * 2 * sizeof(float), stream);
  edge_kernel<<<dim3((NTOT / 64) * MSPLIT), dim3(256), 0, stream>>>(
      h_l, x_l, h_r, x_r, W1, b1, W2, b2, num_g, den_g);
  node_kernel<<<dim3(NTOT / 4), dim3(256), 0, stream>>>(
      h_l, num_g, den_g, Wn1, bn1, lng, lnb, Wn2, bn2, (float*)d_out);
}

// Round 8
// 248.692 us; speedup vs baseline: 1.0428x; 1.0428x over previous
//
#include <hip/hip_runtime.h>
#include <hip/hip_bf16.h>

// INPUTS/OUTPUT ARE FLOAT32 (R1/R3/R4 NaN'd reading them as bf16).
// PERF NOTES:
//  - R5: __launch_bounds__(256,4) -> compiler chose VGPR 64, ~50 reg spills,
//    FETCH 514 MB, 2.6x slower. Never declare a waves/EU target that forces
//    a sub-100-VGPR budget here.
//  - R6 vs R7: duration tracks VALU *instruction count* (~2cyc/instr);
//    v_rcp_f32 is ~free vs VALU — rcp batching (R7) added instrs, +15%. Keep
//    the plain rcp-per-element form.
//  - R2/R6: bounds(256,2) capped residency at ~20% occ (2 waves/EU cap);
//    R5's bounds(256,4) showed 43%. R8: bounds(256) only — uncapped.

#define NTOT 2048
#define MTOT 2048
#define MSPLIT 32
#define MCHUNK 64   // == per-block m range: single staging chunk

typedef short bf16x8 __attribute__((ext_vector_type(8)));
typedef float f32x4  __attribute__((ext_vector_type(4)));
typedef int   i32x4  __attribute__((ext_vector_type(4)));

// exp(x) = 2^(x*log2e); sigmoid(x) = 1/(1+2^(-x*log2e))
#define NL2E (-1.4426950408889634f)
// exp(-d2/5) = 2^(d2 * -log2e/5)
#define C1E  (-0.2885390081777927f)

__device__ __forceinline__ float fast_exp2(float x) {
#if __has_builtin(__builtin_amdgcn_exp2f)
  return __builtin_amdgcn_exp2f(x);
#else
  return __exp2f(x);
#endif
}
__device__ __forceinline__ float fast_rcp(float x) {
#if __has_builtin(__builtin_amdgcn_rcpf)
  return __builtin_amdgcn_rcpf(x);
#else
  return 1.0f / x;
#endif
}
__device__ __forceinline__ float fast_rsq(float x) {
#if __has_builtin(__builtin_amdgcn_rsqf)
  return __builtin_amdgcn_rsqf(x);
#else
  return rsqrtf(x);
#endif
}

// f32 -> bf16 raw bits, round-to-nearest-even (for MFMA B fragments)
__device__ __forceinline__ short to_bf16_rne(float x) {
  union { float f; unsigned u; } v; v.f = x;
  unsigned r = v.u + 0x7FFFu + ((v.u >> 16) & 1u);
  return (short)(r >> 16);
}

// pack two f32 -> two bf16 (round-half-up) in one u32 (lo in low half).
__device__ __forceinline__ unsigned pack_bf16_rn(float lo, float hi) {
  union { float f; unsigned u; } a, b;
  a.f = lo; b.f = hi;
  unsigned au = a.u + 0x8000u, bu = b.u + 0x8000u;
#if __has_builtin(__builtin_amdgcn_perm)
  return __builtin_amdgcn_perm(bu, au, 0x07060302u);
#else
  return (au >> 16) | (bu & 0xffff0000u);
#endif
}

// ---------------------------------------------------------------------------
// Edge phase: per wave, 16 n-rows; loop over this block's 64-m range.
// Grid: (NTOT/64) * MSPLIT = 1024 blocks of 256.
// ---------------------------------------------------------------------------
__global__ __launch_bounds__(256)
void edge_kernel(const float* __restrict__ h_l,
                 const float* __restrict__ x_l,
                 const float* __restrict__ h_r,
                 const float* __restrict__ x_r,
                 const float* __restrict__ W1,
                 const float* __restrict__ b1,
                 const float* __restrict__ W2,
                 const float* __restrict__ b2,
                 float* __restrict__ num_g,
                 float* __restrict__ den_g) {
  __shared__ float hr_s[MCHUNK][64];  // h_r chunk (16 KB)
  __shared__ float xr_s[MCHUNK][8];   // x_r(3), r_p(3), pad (2 KB)

  const int tid  = threadIdx.x;
  const int wave = tid >> 6;
  const int lane = tid & 63;
  const int l15  = lane & 15;
  const int quad = lane >> 4;

  const int nblk   = blockIdx.x / MSPLIT;
  const int msplit = blockIdx.x % MSPLIT;
  const int n0     = nblk * 64 + wave * 16;
  const int mBase  = msplit * MCHUNK;

  // per-lane A-row n
  const int nA = n0 + l15;
  const float xl0 = x_l[nA * 3 + 0];
  const float xl1 = x_l[nA * 3 + 1];
  const float xl2 = x_l[nA * 3 + 2];
  const float lp0 = h_l[nA * 64 + 61];
  const float lp1 = h_l[nA * 64 + 62];
  const float lp2 = h_l[nA * 64 + 63];

  // layer-1 weights for this lane's 16 h1 columns (h1 = quad*8+j and 32+quad*8+j)
  float w1d[16], w1h[16], w1y[16], b1p[16];
#pragma unroll
  for (int j = 0; j < 8; ++j) {
    const int ha = quad * 8 + j, hb = 32 + quad * 8 + j;
    w1d[j] = W1[0 * 64 + ha];   w1d[8 + j] = W1[0 * 64 + hb];
    w1h[j] = W1[1 * 64 + ha];   w1h[8 + j] = W1[1 * 64 + hb];
    w1y[j] = W1[2 * 64 + ha];   w1y[8 + j] = W1[2 * 64 + hb];
    // edge_raw[3] == 1 -> fold W1 row 3 into bias
    b1p[j]     = b1[ha] + W1[3 * 64 + ha];
    b1p[8 + j] = b1[hb] + W1[3 * 64 + hb];
  }

  // W2 B-frags (bf16): B[k = half*32 + quad*8 + j][col = c*16 + l15]
  bf16x8 Bfrag[4][2];
#pragma unroll
  for (int c = 0; c < 4; ++c) {
#pragma unroll
    for (int h = 0; h < 2; ++h) {
      bf16x8 f;
#pragma unroll
      for (int j = 0; j < 8; ++j) {
        const int k = h * 32 + quad * 8 + j;
        f[j] = to_bf16_rne(W2[k * 64 + c * 16 + l15]);
      }
      Bfrag[c][h] = f;
    }
  }

  // b2 folded into sigmoid exp-arg: arg = e*NL2E + NL2E*b2[h2]
  float b2c[4];
#pragma unroll
  for (int c = 0; c < 4; ++c) b2c[c] = NL2E * b2[c * 16 + l15];

  // stage h_r chunk + x_r/r_p chunk
  for (int idx = tid; idx < MCHUNK * 64; idx += 256) {
    const int mm = idx >> 6, hh = idx & 63;
    hr_s[mm][hh] = h_r[(mBase + mm) * 64 + hh];
  }
  for (int idx = tid; idx < MCHUNK * 8; idx += 256) {
    const int mm = idx >> 3, k = idx & 7;
    float v = 0.f;
    const int m = mBase + mm;
    if (k < 3)      v = x_r[m * 3 + k];
    else if (k < 6) v = h_r[m * 64 + 61 + (k - 3)];
    xr_s[mm][k] = v;
  }

  const f32x4 zero4 = {0.f, 0.f, 0.f, 0.f};
  float numr[4][4], denr[4][4];
#pragma unroll
  for (int c = 0; c < 4; ++c)
#pragma unroll
    for (int r = 0; r < 4; ++r) { numr[c][r] = 0.f; denr[c][r] = 0.f; }

  __syncthreads();

#pragma unroll 1
  for (int ms = 0; ms < MCHUNK; ++ms) {
    // broadcast per-m values
    const float xr0 = xr_s[ms][0], xr1 = xr_s[ms][1], xr2 = xr_s[ms][2];
    const float rp0 = xr_s[ms][3], rp1 = xr_s[ms][4], rp2 = xr_s[ms][5];
    const float dx = xl0 - xr0, dy = xl1 - xr1, dz = xl2 - xr2;
    const float d2 = fmaf(dz, dz, fmaf(dy, dy, dx * dx));
    const float dist = fast_exp2(d2 * C1E);          // exp(-d2/5)
    const float hb = fmaf(lp1, rp0, lp0 * rp1);
    const float hy = lp2 * rp2;

    // layer 1 + silu, directly in A-frag element order
    float s[16];
#pragma unroll
    for (int j = 0; j < 16; ++j) {
      const float t = fmaf(dist, w1d[j], fmaf(hb, w1h[j], fmaf(hy, w1y[j], b1p[j])));
      s[j] = t * fast_rcp(1.0f + fast_exp2(t * NL2E));  // silu
    }
    i32x4 p0, p1;
    p0.x = pack_bf16_rn(s[0], s[1]);   p0.y = pack_bf16_rn(s[2], s[3]);
    p0.z = pack_bf16_rn(s[4], s[5]);   p0.w = pack_bf16_rn(s[6], s[7]);
    p1.x = pack_bf16_rn(s[8], s[9]);   p1.y = pack_bf16_rn(s[10], s[11]);
    p1.z = pack_bf16_rn(s[12], s[13]); p1.w = pack_bf16_rn(s[14], s[15]);
    const bf16x8 A0 = __builtin_bit_cast(bf16x8, p0);
    const bf16x8 A1 = __builtin_bit_cast(bf16x8, p1);

    f32x4 acc[4];
#pragma unroll
    for (int c = 0; c < 4; ++c) {
      acc[c] = __builtin_amdgcn_mfma_f32_16x16x32_bf16(A0, Bfrag[c][0], zero4, 0, 0, 0);
      acc[c] = __builtin_amdgcn_mfma_f32_16x16x32_bf16(A1, Bfrag[c][1], acc[c], 0, 0, 0);
    }

    // sigmoid + accumulate: lane holds e[n = n0+quad*4+r][h2 = c*16+l15]
#pragma unroll
    for (int c = 0; c < 4; ++c) {
      const float hrv = hr_s[ms][c * 16 + l15];
#pragma unroll
      for (int r = 0; r < 4; ++r) {
        const float w = fast_rcp(1.0f + fast_exp2(fmaf(acc[c][r], NL2E, b2c[c])));
        numr[c][r] = fmaf(w, hrv, numr[c][r]);
        denr[c][r] += w;
      }
    }
  }

#pragma unroll
  for (int c = 0; c < 4; ++c)
#pragma unroll
    for (int r = 0; r < 4; ++r) {
      const int n = n0 + quad * 4 + r;
      const int h2 = c * 16 + l15;
      atomicAdd(&num_g[n * 64 + h2], numr[c][r]);
      atomicAdd(&den_g[n * 64 + h2], denr[c][r]);
    }
}

// ---------------------------------------------------------------------------
// Node phase: one wave per row. h_agg = num/(den+1e-6); z = cat(h_l,h_agg)@Wn1
// + bn1 -> LN -> silu -> @Wn2 + bn2; out = h_l + z.
// ---------------------------------------------------------------------------
__global__ __launch_bounds__(256)
void node_kernel(const float* __restrict__ h_l,
                 const float* __restrict__ num_g,
                 const float* __restrict__ den_g,
                 const float* __restrict__ Wn1,
                 const float* __restrict__ bn1,
                 const float* __restrict__ ln_g,
                 const float* __restrict__ ln_b,
                 const float* __restrict__ Wn2,
                 const float* __restrict__ bn2,
                 float* __restrict__ out) {
  __shared__ float Wn1_s[128 * 64];
  __shared__ float Wn2_s[64 * 64];
  __shared__ float xbuf[4][128];
  __shared__ float zbuf[4][64];

  const int tid = threadIdx.x;
  for (int i = tid; i < 128 * 64; i += 256) Wn1_s[i] = Wn1[i];
  for (int i = tid; i < 64 * 64; i += 256) Wn2_s[i] = Wn2[i];

  const int wave = tid >> 6, lane = tid & 63;
  const int row = blockIdx.x * 4 + wave;

  const float hl = h_l[row * 64 + lane];
  const float dn = den_g[row * 64 + lane] + 1e-6f;
  const float hagg = num_g[row * 64 + lane] * fast_rcp(dn);
  xbuf[wave][lane] = hl;
  xbuf[wave][64 + lane] = hagg;
  __syncthreads();

  float t = bn1[lane];
#pragma unroll 8
  for (int k = 0; k < 128; ++k) t = fmaf(xbuf[wave][k], Wn1_s[k * 64 + lane], t);

  float s1 = t, s2 = t * t;
#pragma unroll
  for (int off = 32; off; off >>= 1) {
    s1 += __shfl_xor(s1, off);
    s2 += __shfl_xor(s2, off);
  }
  const float mu = s1 * 0.015625f;
  const float var = fmaf(s2, 0.015625f, -mu * mu);
  const float rs = fast_rsq(var + 1e-5f);
  const float zn = fmaf((t - mu) * rs, ln_g[lane], ln_b[lane]);
  const float sz = zn * fast_rcp(1.0f + fast_exp2(zn * NL2E));  // silu
  zbuf[wave][lane] = sz;
  __syncthreads();

  float o = bn2[lane];
#pragma unroll 8
  for (int k = 0; k < 64; ++k) o = fmaf(zbuf[wave][k], Wn2_s[k * 64 + lane], o);

  out[row * 64 + lane] = hl + o;
}

extern "C" void kernel_launch(void* const* d_in, const int* in_sizes, int n_in,
                              void* d_out, int out_size, void* d_ws, size_t ws_size,
                              hipStream_t stream) {
  const float* h_l = (const float*)d_in[0];
  const float* x_l = (const float*)d_in[1];
  const float* h_r = (const float*)d_in[2];
  const float* x_r = (const float*)d_in[3];
  const float* W1  = (const float*)d_in[4];
  const float* b1  = (const float*)d_in[5];
  const float* W2  = (const float*)d_in[6];
  const float* b2  = (const float*)d_in[7];
  const float* Wn1 = (const float*)d_in[8];
  const float* bn1 = (const float*)d_in[9];
  const float* lng = (const float*)d_in[10];
  const float* lnb = (const float*)d_in[11];
  const float* Wn2 = (const float*)d_in[12];
  const float* bn2 = (const float*)d_in[13];

  float* num_g = (float*)d_ws;
  float* den_g = num_g + (size_t)NTOT * 64;

  hipMemsetAsync(d_ws, 0, (size_t)NTOT * 64 * 2 * sizeof(float), stream);
  edge_kernel<<<dim3((NTOT / 64) * MSPLIT), dim3(256), 0, stream>>>(
      h_l, x_l, h_r, x_r, W1, b1, W2, b2, num_g, den_g);
  node_kernel<<<dim3(NTOT / 4), dim3(256), 0, stream>>>(
      h_l, num_g, den_g, Wn1, bn1, lng, lnb, Wn2, bn2, (float*)d_out);
}

// Round 9
// 238.501 us; speedup vs baseline: 1.0873x; 1.0427x over previous
//
#include <hip/hip_runtime.h>
#include <hip/hip_bf16.h>

// INPUTS/OUTPUT ARE FLOAT32 (R1/R3/R4 NaN'd reading them as bf16).
// PERF NOTES:
//  - R5: __launch_bounds__(256,4) -> VGPR 64, ~50 reg spills, FETCH 514 MB,
//    2.6x slower. R8: no bounds clause -> VGPR 104, 178.5 us (worse than
//    R6's (256,2) @ 96 VGPR, 170 us). Keep (256,2).
//  - R6 vs R7 vs R8: duration ~ instr_count * 3.3 cyc (uniform VALU/trans);
//    ~40% is latency bubbles at ~20% occupancy. R9: unroll m-loop by 2 for
//    cross-iteration ILP to fill bubbles (was pinned to unroll 1).

#define NTOT 2048
#define MTOT 2048
#define MSPLIT 32
#define MCHUNK 64   // == per-block m range: single staging chunk

typedef short bf16x8 __attribute__((ext_vector_type(8)));
typedef float f32x4  __attribute__((ext_vector_type(4)));
typedef int   i32x4  __attribute__((ext_vector_type(4)));

// exp(x) = 2^(x*log2e); sigmoid(x) = 1/(1+2^(-x*log2e))
#define NL2E (-1.4426950408889634f)
// exp(-d2/5) = 2^(d2 * -log2e/5)
#define C1E  (-0.2885390081777927f)

__device__ __forceinline__ float fast_exp2(float x) {
#if __has_builtin(__builtin_amdgcn_exp2f)
  return __builtin_amdgcn_exp2f(x);
#else
  return __exp2f(x);
#endif
}
__device__ __forceinline__ float fast_rcp(float x) {
#if __has_builtin(__builtin_amdgcn_rcpf)
  return __builtin_amdgcn_rcpf(x);
#else
  return 1.0f / x;
#endif
}
__device__ __forceinline__ float fast_rsq(float x) {
#if __has_builtin(__builtin_amdgcn_rsqf)
  return __builtin_amdgcn_rsqf(x);
#else
  return rsqrtf(x);
#endif
}

// f32 -> bf16 raw bits, round-to-nearest-even (for MFMA B fragments)
__device__ __forceinline__ short to_bf16_rne(float x) {
  union { float f; unsigned u; } v; v.f = x;
  unsigned r = v.u + 0x7FFFu + ((v.u >> 16) & 1u);
  return (short)(r >> 16);
}

// pack two f32 -> two bf16 (round-half-up) in one u32 (lo in low half).
__device__ __forceinline__ unsigned pack_bf16_rn(float lo, float hi) {
  union { float f; unsigned u; } a, b;
  a.f = lo; b.f = hi;
  unsigned au = a.u + 0x8000u, bu = b.u + 0x8000u;
#if __has_builtin(__builtin_amdgcn_perm)
  return __builtin_amdgcn_perm(bu, au, 0x07060302u);
#else
  return (au >> 16) | (bu & 0xffff0000u);
#endif
}

// ---------------------------------------------------------------------------
// Edge phase: per wave, 16 n-rows; loop over this block's 64-m range.
// Grid: (NTOT/64) * MSPLIT = 1024 blocks of 256.
// ---------------------------------------------------------------------------
__global__ __launch_bounds__(256, 2)
void edge_kernel(const float* __restrict__ h_l,
                 const float* __restrict__ x_l,
                 const float* __restrict__ h_r,
                 const float* __restrict__ x_r,
                 const float* __restrict__ W1,
                 const float* __restrict__ b1,
                 const float* __restrict__ W2,
                 const float* __restrict__ b2,
                 float* __restrict__ num_g,
                 float* __restrict__ den_g) {
  __shared__ float hr_s[MCHUNK][64];  // h_r chunk (16 KB)
  __shared__ float xr_s[MCHUNK][8];   // x_r(3), r_p(3), pad (2 KB)

  const int tid  = threadIdx.x;
  const int wave = tid >> 6;
  const int lane = tid & 63;
  const int l15  = lane & 15;
  const int quad = lane >> 4;

  const int nblk   = blockIdx.x / MSPLIT;
  const int msplit = blockIdx.x % MSPLIT;
  const int n0     = nblk * 64 + wave * 16;
  const int mBase  = msplit * MCHUNK;

  // per-lane A-row n
  const int nA = n0 + l15;
  const float xl0 = x_l[nA * 3 + 0];
  const float xl1 = x_l[nA * 3 + 1];
  const float xl2 = x_l[nA * 3 + 2];
  const float lp0 = h_l[nA * 64 + 61];
  const float lp1 = h_l[nA * 64 + 62];
  const float lp2 = h_l[nA * 64 + 63];

  // layer-1 weights for this lane's 16 h1 columns (h1 = quad*8+j and 32+quad*8+j)
  float w1d[16], w1h[16], w1y[16], b1p[16];
#pragma unroll
  for (int j = 0; j < 8; ++j) {
    const int ha = quad * 8 + j, hb = 32 + quad * 8 + j;
    w1d[j] = W1[0 * 64 + ha];   w1d[8 + j] = W1[0 * 64 + hb];
    w1h[j] = W1[1 * 64 + ha];   w1h[8 + j] = W1[1 * 64 + hb];
    w1y[j] = W1[2 * 64 + ha];   w1y[8 + j] = W1[2 * 64 + hb];
    // edge_raw[3] == 1 -> fold W1 row 3 into bias
    b1p[j]     = b1[ha] + W1[3 * 64 + ha];
    b1p[8 + j] = b1[hb] + W1[3 * 64 + hb];
  }

  // W2 B-frags (bf16): B[k = half*32 + quad*8 + j][col = c*16 + l15]
  bf16x8 Bfrag[4][2];
#pragma unroll
  for (int c = 0; c < 4; ++c) {
#pragma unroll
    for (int h = 0; h < 2; ++h) {
      bf16x8 f;
#pragma unroll
      for (int j = 0; j < 8; ++j) {
        const int k = h * 32 + quad * 8 + j;
        f[j] = to_bf16_rne(W2[k * 64 + c * 16 + l15]);
      }
      Bfrag[c][h] = f;
    }
  }

  // b2 folded into sigmoid exp-arg: arg = e*NL2E + NL2E*b2[h2]
  float b2c[4];
#pragma unroll
  for (int c = 0; c < 4; ++c) b2c[c] = NL2E * b2[c * 16 + l15];

  // stage h_r chunk + x_r/r_p chunk
  for (int idx = tid; idx < MCHUNK * 64; idx += 256) {
    const int mm = idx >> 6, hh = idx & 63;
    hr_s[mm][hh] = h_r[(mBase + mm) * 64 + hh];
  }
  for (int idx = tid; idx < MCHUNK * 8; idx += 256) {
    const int mm = idx >> 3, k = idx & 7;
    float v = 0.f;
    const int m = mBase + mm;
    if (k < 3)      v = x_r[m * 3 + k];
    else if (k < 6) v = h_r[m * 64 + 61 + (k - 3)];
    xr_s[mm][k] = v;
  }

  const f32x4 zero4 = {0.f, 0.f, 0.f, 0.f};
  float numr[4][4], denr[4][4];
#pragma unroll
  for (int c = 0; c < 4; ++c)
#pragma unroll
    for (int r = 0; r < 4; ++r) { numr[c][r] = 0.f; denr[c][r] = 0.f; }

  __syncthreads();

#pragma unroll 2
  for (int ms = 0; ms < MCHUNK; ++ms) {
    // broadcast per-m values
    const float xr0 = xr_s[ms][0], xr1 = xr_s[ms][1], xr2 = xr_s[ms][2];
    const float rp0 = xr_s[ms][3], rp1 = xr_s[ms][4], rp2 = xr_s[ms][5];
    const float dx = xl0 - xr0, dy = xl1 - xr1, dz = xl2 - xr2;
    const float d2 = fmaf(dz, dz, fmaf(dy, dy, dx * dx));
    const float dist = fast_exp2(d2 * C1E);          // exp(-d2/5)
    const float hb = fmaf(lp1, rp0, lp0 * rp1);
    const float hy = lp2 * rp2;

    // layer 1 + silu, directly in A-frag element order
    float s[16];
#pragma unroll
    for (int j = 0; j < 16; ++j) {
      const float t = fmaf(dist, w1d[j], fmaf(hb, w1h[j], fmaf(hy, w1y[j], b1p[j])));
      s[j] = t * fast_rcp(1.0f + fast_exp2(t * NL2E));  // silu
    }
    i32x4 p0, p1;
    p0.x = pack_bf16_rn(s[0], s[1]);   p0.y = pack_bf16_rn(s[2], s[3]);
    p0.z = pack_bf16_rn(s[4], s[5]);   p0.w = pack_bf16_rn(s[6], s[7]);
    p1.x = pack_bf16_rn(s[8], s[9]);   p1.y = pack_bf16_rn(s[10], s[11]);
    p1.z = pack_bf16_rn(s[12], s[13]); p1.w = pack_bf16_rn(s[14], s[15]);
    const bf16x8 A0 = __builtin_bit_cast(bf16x8, p0);
    const bf16x8 A1 = __builtin_bit_cast(bf16x8, p1);

    f32x4 acc[4];
#pragma unroll
    for (int c = 0; c < 4; ++c) {
      acc[c] = __builtin_amdgcn_mfma_f32_16x16x32_bf16(A0, Bfrag[c][0], zero4, 0, 0, 0);
      acc[c] = __builtin_amdgcn_mfma_f32_16x16x32_bf16(A1, Bfrag[c][1], acc[c], 0, 0, 0);
    }

    // sigmoid + accumulate: lane holds e[n = n0+quad*4+r][h2 = c*16+l15]
#pragma unroll
    for (int c = 0; c < 4; ++c) {
      const float hrv = hr_s[ms][c * 16 + l15];
#pragma unroll
      for (int r = 0; r < 4; ++r) {
        const float w = fast_rcp(1.0f + fast_exp2(fmaf(acc[c][r], NL2E, b2c[c])));
        numr[c][r] = fmaf(w, hrv, numr[c][r]);
        denr[c][r] += w;
      }
    }
  }

#pragma unroll
  for (int c = 0; c < 4; ++c)
#pragma unroll
    for (int r = 0; r < 4; ++r) {
      const int n = n0 + quad * 4 + r;
      const int h2 = c * 16 + l15;
      atomicAdd(&num_g[n * 64 + h2], numr[c][r]);
      atomicAdd(&den_g[n * 64 + h2], denr[c][r]);
    }
}

// ---------------------------------------------------------------------------
// Node phase: one wave per row. h_agg = num/(den+1e-6); z = cat(h_l,h_agg)@Wn1
// + bn1 -> LN -> silu -> @Wn2 + bn2; out = h_l + z.
// ---------------------------------------------------------------------------
__global__ __launch_bounds__(256)
void node_kernel(const float* __restrict__ h_l,
                 const float* __restrict__ num_g,
                 const float* __restrict__ den_g,
                 const float* __restrict__ Wn1,
                 const float* __restrict__ bn1,
                 const float* __restrict__ ln_g,
                 const float* __restrict__ ln_b,
                 const float* __restrict__ Wn2,
                 const float* __restrict__ bn2,
                 float* __restrict__ out) {
  __shared__ float Wn1_s[128 * 64];
  __shared__ float Wn2_s[64 * 64];
  __shared__ float xbuf[4][128];
  __shared__ float zbuf[4][64];

  const int tid = threadIdx.x;
  for (int i = tid; i < 128 * 64; i += 256) Wn1_s[i] = Wn1[i];
  for (int i = tid; i < 64 * 64; i += 256) Wn2_s[i] = Wn2[i];

  const int wave = tid >> 6, lane = tid & 63;
  const int row = blockIdx.x * 4 + wave;

  const float hl = h_l[row * 64 + lane];
  const float dn = den_g[row * 64 + lane] + 1e-6f;
  const float hagg = num_g[row * 64 + lane] * fast_rcp(dn);
  xbuf[wave][lane] = hl;
  xbuf[wave][64 + lane] = hagg;
  __syncthreads();

  float t = bn1[lane];
#pragma unroll 8
  for (int k = 0; k < 128; ++k) t = fmaf(xbuf[wave][k], Wn1_s[k * 64 + lane], t);

  float s1 = t, s2 = t * t;
#pragma unroll
  for (int off = 32; off; off >>= 1) {
    s1 += __shfl_xor(s1, off);
    s2 += __shfl_xor(s2, off);
  }
  const float mu = s1 * 0.015625f;
  const float var = fmaf(s2, 0.015625f, -mu * mu);
  const float rs = fast_rsq(var + 1e-5f);
  const float zn = fmaf((t - mu) * rs, ln_g[lane], ln_b[lane]);
  const float sz = zn * fast_rcp(1.0f + fast_exp2(zn * NL2E));  // silu
  zbuf[wave][lane] = sz;
  __syncthreads();

  float o = bn2[lane];
#pragma unroll 8
  for (int k = 0; k < 64; ++k) o = fmaf(zbuf[wave][k], Wn2_s[k * 64 + lane], o);

  out[row * 64 + lane] = hl + o;
}

extern "C" void kernel_launch(void* const* d_in, const int* in_sizes, int n_in,
                              void* d_out, int out_size, void* d_ws, size_t ws_size,
                              hipStream_t stream) {
  const float* h_l = (const float*)d_in[0];
  const float* x_l = (const float*)d_in[1];
  const float* h_r = (const float*)d_in[2];
  const float* x_r = (const float*)d_in[3];
  const float* W1  = (const float*)d_in[4];
  const float* b1  = (const float*)d_in[5];
  const float* W2  = (const float*)d_in[6];
  const float* b2  = (const float*)d_in[7];
  const float* Wn1 = (const float*)d_in[8];
  const float* bn1 = (const float*)d_in[9];
  const float* lng = (const float*)d_in[10];
  const float* lnb = (const float*)d_in[11];
  const float* Wn2 = (const float*)d_in[12];
  const float* bn2 = (const float*)d_in[13];

  float* num_g = (float*)d_ws;
  float* den_g = num_g + (size_t)NTOT * 64;

  hipMemsetAsync(d_ws, 0, (size_t)NTOT * 64 * 2 * sizeof(float), stream);
  edge_kernel<<<dim3((NTOT / 64) * MSPLIT), dim3(256), 0, stream>>>(
      h_l, x_l, h_r, x_r, W1, b1, W2, b2, num_g, den_g);
  node_kernel<<<dim3(NTOT / 4), dim3(256), 0, stream>>>(
      h_l, num_g, den_g, Wn1, bn1, lng, lnb, Wn2, bn2, (float*)d_out);
}

// Round 10
// 223.608 us; speedup vs baseline: 1.1597x; 1.0666x over previous
//
#include <hip/hip_runtime.h>
#include <hip/hip_bf16.h>

// INPUTS/OUTPUT ARE FLOAT32 (R1/R3/R4 NaN'd reading them as bf16).
// PERF NOTES:
//  - R5: bounds(256,4) -> VGPR 64, spills, FETCH 514 MB, 2.6x slower.
//    R8: no bounds -> VGPR 104, 178 us. Keep (256,2) @ ~96-110 VGPR.
//  - R6/R7/R8/R9: duration ~ VALU-slot instr count * 3.3 cyc, uniform
//    across VALU and trans (rcp/exp2 not specially expensive). Occupancy
//    pinned ~20% regardless of grid/bounds. Only instruction removal helps.
//  - R10: pack elementwise math into v_pk_*_f32 (VOP3P) via float2 vector
//    types + __builtin_elementwise_fma: ~264 -> ~185 instr/m-step.

#define NTOT 2048
#define MTOT 2048
#define MSPLIT 32
#define MCHUNK 64   // == per-block m range: single staging chunk

typedef short bf16x8 __attribute__((ext_vector_type(8)));
typedef float f32x4  __attribute__((ext_vector_type(4)));
typedef float f32x2  __attribute__((ext_vector_type(2)));
typedef int   i32x4  __attribute__((ext_vector_type(4)));

// exp(x) = 2^(x*log2e); sigmoid(x) = 1/(1+2^(-x*log2e))
#define NL2E (-1.4426950408889634f)
// exp(-d2/5) = 2^(d2 * -log2e/5)
#define C1E  (-0.2885390081777927f)

__device__ __forceinline__ float fast_exp2(float x) {
#if __has_builtin(__builtin_amdgcn_exp2f)
  return __builtin_amdgcn_exp2f(x);
#else
  return __exp2f(x);
#endif
}
__device__ __forceinline__ float fast_rcp(float x) {
#if __has_builtin(__builtin_amdgcn_rcpf)
  return __builtin_amdgcn_rcpf(x);
#else
  return 1.0f / x;
#endif
}
__device__ __forceinline__ float fast_rsq(float x) {
#if __has_builtin(__builtin_amdgcn_rsqf)
  return __builtin_amdgcn_rsqf(x);
#else
  return rsqrtf(x);
#endif
}
__device__ __forceinline__ f32x2 pk_fma(f32x2 a, f32x2 b, f32x2 c) {
  return __builtin_elementwise_fma(a, b, c);
}

// f32 -> bf16 raw bits, round-to-nearest-even (for MFMA B fragments)
__device__ __forceinline__ short to_bf16_rne(float x) {
  union { float f; unsigned u; } v; v.f = x;
  unsigned r = v.u + 0x7FFFu + ((v.u >> 16) & 1u);
  return (short)(r >> 16);
}

// pack two f32 -> two bf16 (round-half-up) in one u32 (lo in low half).
__device__ __forceinline__ unsigned pack_bf16_rn(float lo, float hi) {
  union { float f; unsigned u; } a, b;
  a.f = lo; b.f = hi;
  unsigned au = a.u + 0x8000u, bu = b.u + 0x8000u;
#if __has_builtin(__builtin_amdgcn_perm)
  return __builtin_amdgcn_perm(bu, au, 0x07060302u);
#else
  return (au >> 16) | (bu & 0xffff0000u);
#endif
}

// ---------------------------------------------------------------------------
// Edge phase: per wave, 16 n-rows; loop over this block's 64-m range.
// Grid: (NTOT/64) * MSPLIT = 1024 blocks of 256.
// ---------------------------------------------------------------------------
__global__ __launch_bounds__(256, 2)
void edge_kernel(const float* __restrict__ h_l,
                 const float* __restrict__ x_l,
                 const float* __restrict__ h_r,
                 const float* __restrict__ x_r,
                 const float* __restrict__ W1,
                 const float* __restrict__ b1,
                 const float* __restrict__ W2,
                 const float* __restrict__ b2,
                 float* __restrict__ num_g,
                 float* __restrict__ den_g) {
  __shared__ float hr_s[MCHUNK][64];  // h_r chunk (16 KB)
  __shared__ float xr_s[MCHUNK][8];   // x_r(3), r_p(3), pad (2 KB)

  const int tid  = threadIdx.x;
  const int wave = tid >> 6;
  const int lane = tid & 63;
  const int l15  = lane & 15;
  const int quad = lane >> 4;

  const int nblk   = blockIdx.x / MSPLIT;
  const int msplit = blockIdx.x % MSPLIT;
  const int n0     = nblk * 64 + wave * 16;
  const int mBase  = msplit * MCHUNK;

  // per-lane A-row n
  const int nA = n0 + l15;
  const float xl0 = x_l[nA * 3 + 0];
  const float xl1 = x_l[nA * 3 + 1];
  const float xl2 = x_l[nA * 3 + 2];
  const float lp0 = h_l[nA * 64 + 61];
  const float lp1 = h_l[nA * 64 + 62];
  const float lp2 = h_l[nA * 64 + 63];

  // layer-1 weights as j-pairs (j pairs (2p,2p+1) of this lane's 16 h1 cols:
  // h1 = quad*8 + j for j<8, and 32 + quad*8 + (j-8) for j>=8)
  f32x2 w1d2[8], w1h2[8], w1y2[8], b1p2[8];
#pragma unroll
  for (int p = 0; p < 8; ++p) {
    const int j0 = 2 * p, j1 = 2 * p + 1;
    const int hA = (j0 < 8) ? (quad * 8 + j0) : (32 + quad * 8 + (j0 - 8));
    const int hB = (j1 < 8) ? (quad * 8 + j1) : (32 + quad * 8 + (j1 - 8));
    w1d2[p] = f32x2{W1[0 * 64 + hA], W1[0 * 64 + hB]};
    w1h2[p] = f32x2{W1[1 * 64 + hA], W1[1 * 64 + hB]};
    w1y2[p] = f32x2{W1[2 * 64 + hA], W1[2 * 64 + hB]};
    b1p2[p] = f32x2{b1[hA] + W1[3 * 64 + hA], b1[hB] + W1[3 * 64 + hB]};
  }

  // W2 B-frags (bf16): B[k = half*32 + quad*8 + j][col = c*16 + l15]
  bf16x8 Bfrag[4][2];
#pragma unroll
  for (int c = 0; c < 4; ++c) {
#pragma unroll
    for (int h = 0; h < 2; ++h) {
      bf16x8 f;
#pragma unroll
      for (int j = 0; j < 8; ++j) {
        const int k = h * 32 + quad * 8 + j;
        f[j] = to_bf16_rne(W2[k * 64 + c * 16 + l15]);
      }
      Bfrag[c][h] = f;
    }
  }

  // b2 folded into sigmoid exp-arg: arg = e*NL2E + NL2E*b2[h2]
  f32x2 b2c2[4];
#pragma unroll
  for (int c = 0; c < 4; ++c) {
    const float v = NL2E * b2[c * 16 + l15];
    b2c2[c] = f32x2{v, v};
  }

  // stage h_r chunk + x_r/r_p chunk
  for (int idx = tid; idx < MCHUNK * 64; idx += 256) {
    const int mm = idx >> 6, hh = idx & 63;
    hr_s[mm][hh] = h_r[(mBase + mm) * 64 + hh];
  }
  for (int idx = tid; idx < MCHUNK * 8; idx += 256) {
    const int mm = idx >> 3, k = idx & 7;
    float v = 0.f;
    const int m = mBase + mm;
    if (k < 3)      v = x_r[m * 3 + k];
    else if (k < 6) v = h_r[m * 64 + 61 + (k - 3)];
    xr_s[mm][k] = v;
  }

  const f32x4 zero4 = {0.f, 0.f, 0.f, 0.f};
  const f32x2 one2 = {1.f, 1.f};
  const f32x2 nl2e2 = {NL2E, NL2E};
  f32x2 numr2[4][2], denr2[4][2];
#pragma unroll
  for (int c = 0; c < 4; ++c)
#pragma unroll
    for (int h = 0; h < 2; ++h) {
      numr2[c][h] = f32x2{0.f, 0.f};
      denr2[c][h] = f32x2{0.f, 0.f};
    }

  __syncthreads();

#pragma unroll 2
  for (int ms = 0; ms < MCHUNK; ++ms) {
    // broadcast per-m values
    const float xr0 = xr_s[ms][0], xr1 = xr_s[ms][1], xr2 = xr_s[ms][2];
    const float rp0 = xr_s[ms][3], rp1 = xr_s[ms][4], rp2 = xr_s[ms][5];
    const float dx = xl0 - xr0, dy = xl1 - xr1, dz = xl2 - xr2;
    const float d2 = fmaf(dz, dz, fmaf(dy, dy, dx * dx));
    const float dist = fast_exp2(d2 * C1E);          // exp(-d2/5)
    const float hb = fmaf(lp1, rp0, lp0 * rp1);
    const float hy = lp2 * rp2;
    const f32x2 distv = {dist, dist};
    const f32x2 hbv = {hb, hb};
    const f32x2 hyv = {hy, hy};

    // layer 1 + silu, j-pairs packed (v_pk_fma_f32 etc.), A-frag order
    f32x2 s2[8];
#pragma unroll
    for (int p = 0; p < 8; ++p) {
      const f32x2 t2 = pk_fma(distv, w1d2[p],
                       pk_fma(hbv, w1h2[p],
                       pk_fma(hyv, w1y2[p], b1p2[p])));
      const f32x2 a2 = t2 * nl2e2;               // pk_mul
      f32x2 e2;
      e2.x = fast_exp2(a2.x);
      e2.y = fast_exp2(a2.y);
      const f32x2 dden = e2 + one2;              // pk_add
      f32x2 r2;
      r2.x = fast_rcp(dden.x);
      r2.y = fast_rcp(dden.y);
      s2[p] = t2 * r2;                           // pk_mul  (silu = t/(1+e^-t))
    }
    i32x4 p0, p1;
    p0.x = pack_bf16_rn(s2[0].x, s2[0].y);  p0.y = pack_bf16_rn(s2[1].x, s2[1].y);
    p0.z = pack_bf16_rn(s2[2].x, s2[2].y);  p0.w = pack_bf16_rn(s2[3].x, s2[3].y);
    p1.x = pack_bf16_rn(s2[4].x, s2[4].y);  p1.y = pack_bf16_rn(s2[5].x, s2[5].y);
    p1.z = pack_bf16_rn(s2[6].x, s2[6].y);  p1.w = pack_bf16_rn(s2[7].x, s2[7].y);
    const bf16x8 A0 = __builtin_bit_cast(bf16x8, p0);
    const bf16x8 A1 = __builtin_bit_cast(bf16x8, p1);

    f32x4 acc[4];
#pragma unroll
    for (int c = 0; c < 4; ++c) {
      acc[c] = __builtin_amdgcn_mfma_f32_16x16x32_bf16(A0, Bfrag[c][0], zero4, 0, 0, 0);
      acc[c] = __builtin_amdgcn_mfma_f32_16x16x32_bf16(A1, Bfrag[c][1], acc[c], 0, 0, 0);
    }

    // sigmoid + accumulate, r-pairs packed.
    // lane holds e[n = n0+quad*4+r][h2 = c*16+l15], r in acc[c][r].
#pragma unroll
    for (int c = 0; c < 4; ++c) {
      const float hrv = hr_s[ms][c * 16 + l15];
      const f32x2 hrv2 = {hrv, hrv};
#pragma unroll
      for (int h = 0; h < 2; ++h) {
        const f32x2 a2 = {acc[c][2 * h], acc[c][2 * h + 1]};
        const f32x2 arg = pk_fma(a2, nl2e2, b2c2[c]);
        f32x2 e2;
        e2.x = fast_exp2(arg.x);
        e2.y = fast_exp2(arg.y);
        const f32x2 dden = e2 + one2;            // pk_add
        f32x2 w2;
        w2.x = fast_rcp(dden.x);
        w2.y = fast_rcp(dden.y);
        numr2[c][h] = pk_fma(w2, hrv2, numr2[c][h]);
        denr2[c][h] = denr2[c][h] + w2;          // pk_add
      }
    }
  }

#pragma unroll
  for (int c = 0; c < 4; ++c)
#pragma unroll
    for (int h = 0; h < 2; ++h)
#pragma unroll
      for (int k = 0; k < 2; ++k) {
        const int r = 2 * h + k;
        const int n = n0 + quad * 4 + r;
        const int h2 = c * 16 + l15;
        atomicAdd(&num_g[n * 64 + h2], k ? numr2[c][h].y : numr2[c][h].x);
        atomicAdd(&den_g[n * 64 + h2], k ? denr2[c][h].y : denr2[c][h].x);
      }
}

// ---------------------------------------------------------------------------
// Node phase: one wave per row. h_agg = num/(den+1e-6); z = cat(h_l,h_agg)@Wn1
// + bn1 -> LN -> silu -> @Wn2 + bn2; out = h_l + z.
// ---------------------------------------------------------------------------
__global__ __launch_bounds__(256)
void node_kernel(const float* __restrict__ h_l,
                 const float* __restrict__ num_g,
                 const float* __restrict__ den_g,
                 const float* __restrict__ Wn1,
                 const float* __restrict__ bn1,
                 const float* __restrict__ ln_g,
                 const float* __restrict__ ln_b,
                 const float* __restrict__ Wn2,
                 const float* __restrict__ bn2,
                 float* __restrict__ out) {
  __shared__ float Wn1_s[128 * 64];
  __shared__ float Wn2_s[64 * 64];
  __shared__ float xbuf[4][128];
  __shared__ float zbuf[4][64];

  const int tid = threadIdx.x;
  for (int i = tid; i < 128 * 64; i += 256) Wn1_s[i] = Wn1[i];
  for (int i = tid; i < 64 * 64; i += 256) Wn2_s[i] = Wn2[i];

  const int wave = tid >> 6, lane = tid & 63;
  const int row = blockIdx.x * 4 + wave;

  const float hl = h_l[row * 64 + lane];
  const float dn = den_g[row * 64 + lane] + 1e-6f;
  const float hagg = num_g[row * 64 + lane] * fast_rcp(dn);
  xbuf[wave][lane] = hl;
  xbuf[wave][64 + lane] = hagg;
  __syncthreads();

  float t = bn1[lane];
#pragma unroll 8
  for (int k = 0; k < 128; ++k) t = fmaf(xbuf[wave][k], Wn1_s[k * 64 + lane], t);

  float s1 = t, s2 = t * t;
#pragma unroll
  for (int off = 32; off; off >>= 1) {
    s1 += __shfl_xor(s1, off);
    s2 += __shfl_xor(s2, off);
  }
  const float mu = s1 * 0.015625f;
  const float var = fmaf(s2, 0.015625f, -mu * mu);
  const float rs = fast_rsq(var + 1e-5f);
  const float zn = fmaf((t - mu) * rs, ln_g[lane], ln_b[lane]);
  const float sz = zn * fast_rcp(1.0f + fast_exp2(zn * NL2E));  // silu
  zbuf[wave][lane] = sz;
  __syncthreads();

  float o = bn2[lane];
#pragma unroll 8
  for (int k = 0; k < 64; ++k) o = fmaf(zbuf[wave][k], Wn2_s[k * 64 + lane], o);

  out[row * 64 + lane] = hl + o;
}

extern "C" void kernel_launch(void* const* d_in, const int* in_sizes, int n_in,
                              void* d_out, int out_size, void* d_ws, size_t ws_size,
                              hipStream_t stream) {
  const float* h_l = (const float*)d_in[0];
  const float* x_l = (const float*)d_in[1];
  const float* h_r = (const float*)d_in[2];
  const float* x_r = (const float*)d_in[3];
  const float* W1  = (const float*)d_in[4];
  const float* b1  = (const float*)d_in[5];
  const float* W2  = (const float*)d_in[6];
  const float* b2  = (const float*)d_in[7];
  const float* Wn1 = (const float*)d_in[8];
  const float* bn1 = (const float*)d_in[9];
  const float* lng = (const float*)d_in[10];
  const float* lnb = (const float*)d_in[11];
  const float* Wn2 = (const float*)d_in[12];
  const float* bn2 = (const float*)d_in[13];

  float* num_g = (float*)d_ws;
  float* den_g = num_g + (size_t)NTOT * 64;

  hipMemsetAsync(d_ws, 0, (size_t)NTOT * 64 * 2 * sizeof(float), stream);
  edge_kernel<<<dim3((NTOT / 64) * MSPLIT), dim3(256), 0, stream>>>(
      h_l, x_l, h_r, x_r, W1, b1, W2, b2, num_g, den_g);
  node_kernel<<<dim3(NTOT / 4), dim3(256), 0, stream>>>(
      h_l, num_g, den_g, Wn1, bn1, lng, lnb, Wn2, bn2, (float*)d_out);
}

// Round 11
// 217.379 us; speedup vs baseline: 1.1930x; 1.0287x over previous
//
#include <hip/hip_runtime.h>
#include <hip/hip_bf16.h>
#include <hip/hip_fp16.h>

// INPUTS/OUTPUT ARE FLOAT32 (R1/R3/R4 NaN'd reading them as bf16).
// PERF NOTES:
//  - R5: bounds(256,4) -> forced VGPR 64, spills, FETCH 514 MB, 2.6x slower.
//    Keep (256,2) (no forced budget below natural usage).
//  - Cost model (fits R6..R10): cyc/m-step ~ 3.6*VALU + 10.3*trans at ~20%
//    occupancy (2 blocks/CU). Trans (64/m-step) irreducible: 2/activation.
//  - R10: pk_f32 packing -8.5%. R11: f16 datapath for layer1+silu+MFMA:
//    deletes bf16 pack (-24 instr), halves W1 regs (64->32), b128 LDS reads.

#define NTOT 2048
#define MTOT 2048
#define MSPLIT 32
#define MCHUNK 64   // == per-block m range: single staging chunk

typedef _Float16 f16x8 __attribute__((ext_vector_type(8)));
typedef float f32x4  __attribute__((ext_vector_type(4)));
typedef float f32x2  __attribute__((ext_vector_type(2)));
typedef int   i32x4  __attribute__((ext_vector_type(4)));

// exp(x) = 2^(x*log2e); sigmoid(x) = 1/(1+2^(-x*log2e))
#define NL2E (-1.4426950408889634f)
// exp(-d2/5) = 2^(d2 * -log2e/5)
#define C1E  (-0.2885390081777927f)

__device__ __forceinline__ float fast_exp2(float x) {
#if __has_builtin(__builtin_amdgcn_exp2f)
  return __builtin_amdgcn_exp2f(x);
#else
  return __exp2f(x);
#endif
}
__device__ __forceinline__ float fast_rcp(float x) {
#if __has_builtin(__builtin_amdgcn_rcpf)
  return __builtin_amdgcn_rcpf(x);
#else
  return 1.0f / x;
#endif
}
__device__ __forceinline__ float fast_rsq(float x) {
#if __has_builtin(__builtin_amdgcn_rsqf)
  return __builtin_amdgcn_rsqf(x);
#else
  return rsqrtf(x);
#endif
}
__device__ __forceinline__ f32x2 pk_fma(f32x2 a, f32x2 b, f32x2 c) {
  return __builtin_elementwise_fma(a, b, c);
}

// ---------------------------------------------------------------------------
// Edge phase: per wave, 16 n-rows; loop over this block's 64-m range.
// layer1+silu in packed f16 -> f16 A-frags (no pack step) -> f16 MFMA ->
// sigmoid f32 -> num/den f32 regs -> atomicAdd.
// Grid: (NTOT/64) * MSPLIT = 1024 blocks of 256.
// ---------------------------------------------------------------------------
__global__ __launch_bounds__(256, 2)
void edge_kernel(const float* __restrict__ h_l,
                 const float* __restrict__ x_l,
                 const float* __restrict__ h_r,
                 const float* __restrict__ x_r,
                 const float* __restrict__ W1,
                 const float* __restrict__ b1,
                 const float* __restrict__ W2,
                 const float* __restrict__ b2,
                 float* __restrict__ num_g,
                 float* __restrict__ den_g) {
  // hrT[ms][l15*4 + c] = h_r[m][c*16 + l15]  (per-lane float4 -> ds_read_b128)
  __shared__ float hrT[MCHUNK][64];   // 16 KB
  __shared__ float xr_s[MCHUNK][8];   // x_r(3), r_p(3), pad (2 KB)

  const int tid  = threadIdx.x;
  const int wave = tid >> 6;
  const int lane = tid & 63;
  const int l15  = lane & 15;
  const int quad = lane >> 4;

  const int nblk   = blockIdx.x / MSPLIT;
  const int msplit = blockIdx.x % MSPLIT;
  const int n0     = nblk * 64 + wave * 16;
  const int mBase  = msplit * MCHUNK;

  // per-lane A-row n
  const int nA = n0 + l15;
  const float xl0 = x_l[nA * 3 + 0];
  const float xl1 = x_l[nA * 3 + 1];
  const float xl2 = x_l[nA * 3 + 2];
  const float lp0 = h_l[nA * 64 + 61];
  const float lp1 = h_l[nA * 64 + 62];
  const float lp2 = h_l[nA * 64 + 63];

  // layer-1 weights as packed f16 pairs over j (this lane's 16 h1 cols:
  // h1 = quad*8 + j for j<8, 32 + quad*8 + (j-8) for j>=8)
  __half2 w1d2[8], w1h2[8], w1y2[8], b1p2[8];
#pragma unroll
  for (int p = 0; p < 8; ++p) {
    const int j0 = 2 * p, j1 = 2 * p + 1;
    const int hA = (j0 < 8) ? (quad * 8 + j0) : (32 + quad * 8 + (j0 - 8));
    const int hB = (j1 < 8) ? (quad * 8 + j1) : (32 + quad * 8 + (j1 - 8));
    w1d2[p] = __floats2half2_rn(W1[0 * 64 + hA], W1[0 * 64 + hB]);
    w1h2[p] = __floats2half2_rn(W1[1 * 64 + hA], W1[1 * 64 + hB]);
    w1y2[p] = __floats2half2_rn(W1[2 * 64 + hA], W1[2 * 64 + hB]);
    // edge_raw[3] == 1 -> fold W1 row 3 into bias
    b1p2[p] = __floats2half2_rn(b1[hA] + W1[3 * 64 + hA],
                                b1[hB] + W1[3 * 64 + hB]);
  }

  // W2 B-frags (f16): B[k = half*32 + quad*8 + j][col = c*16 + l15]
  f16x8 Bfrag[4][2];
#pragma unroll
  for (int c = 0; c < 4; ++c) {
#pragma unroll
    for (int h = 0; h < 2; ++h) {
      f16x8 f;
#pragma unroll
      for (int j = 0; j < 8; ++j) {
        const int k = h * 32 + quad * 8 + j;
        f[j] = (_Float16)W2[k * 64 + c * 16 + l15];
      }
      Bfrag[c][h] = f;
    }
  }

  // b2 folded into sigmoid exp-arg: arg = e*NL2E + NL2E*b2[h2]
  f32x2 b2c2[4];
#pragma unroll
  for (int c = 0; c < 4; ++c) {
    const float v = NL2E * b2[c * 16 + l15];
    b2c2[c] = f32x2{v, v};
  }

  // stage h_r chunk (transposed groups of 4) + x_r/r_p chunk
  for (int idx = tid; idx < MCHUNK * 64; idx += 256) {
    const int mm = idx >> 6, w = idx & 63;
    const int i = w >> 2, c = w & 3;
    hrT[mm][w] = h_r[(mBase + mm) * 64 + c * 16 + i];
  }
  for (int idx = tid; idx < MCHUNK * 8; idx += 256) {
    const int mm = idx >> 3, k = idx & 7;
    float v = 0.f;
    const int m = mBase + mm;
    if (k < 3)      v = x_r[m * 3 + k];
    else if (k < 6) v = h_r[m * 64 + 61 + (k - 3)];
    xr_s[mm][k] = v;
  }

  const f32x4 zero4 = {0.f, 0.f, 0.f, 0.f};
  const f32x2 one2 = {1.f, 1.f};
  const f32x2 nl2e2 = {NL2E, NL2E};
  const __half2 nl2eh = __float2half2_rn(NL2E);
  const __half2 oneh  = __float2half2_rn(1.0f);
  f32x2 numr2[4][2], denr2[4][2];
#pragma unroll
  for (int c = 0; c < 4; ++c)
#pragma unroll
    for (int h = 0; h < 2; ++h) {
      numr2[c][h] = f32x2{0.f, 0.f};
      denr2[c][h] = f32x2{0.f, 0.f};
    }

  __syncthreads();

#pragma unroll 2
  for (int ms = 0; ms < MCHUNK; ++ms) {
    // broadcast per-m values (same-address LDS reads, vectorized)
    const f32x4 xa = *(const f32x4*)&xr_s[ms][0];   // xr0 xr1 xr2 rp0
    const f32x2 xb = *(const f32x2*)&xr_s[ms][4];   // rp1 rp2
    const float dx = xl0 - xa[0], dy = xl1 - xa[1], dz = xl2 - xa[2];
    const float d2 = fmaf(dz, dz, fmaf(dy, dy, dx * dx));
    const float dist = fast_exp2(d2 * C1E);          // exp(-d2/5)
    const float hb = fmaf(lp1, xa[3], lp0 * xb[0]);
    const float hy = lp2 * xb[1];
    const __half2 dist2 = __float2half2_rn(dist);
    const __half2 hb2 = __float2half2_rn(hb);
    const __half2 hy2 = __float2half2_rn(hy);

    // layer 1 + silu, packed f16, A-frag element order.
    // f16 overflow in e2 (t < ~-11.5) -> inf -> rcp 0 -> s=0 == silu tail. OK.
    __half2 s2[8];
#pragma unroll
    for (int p = 0; p < 8; ++p) {
      const __half2 t2 = __hfma2(dist2, w1d2[p],
                         __hfma2(hb2, w1h2[p],
                         __hfma2(hy2, w1y2[p], b1p2[p])));
      const __half2 a2 = __hmul2(t2, nl2eh);
      const __half2 e2 = h2exp2(a2);
      const __half2 dden = __hadd2(e2, oneh);
      const __half2 r2 = h2rcp(dden);
      s2[p] = __hmul2(t2, r2);                 // silu = t/(1+2^(t*NL2E))
    }
    i32x4 p0, p1;
    p0.x = __builtin_bit_cast(int, s2[0]);  p0.y = __builtin_bit_cast(int, s2[1]);
    p0.z = __builtin_bit_cast(int, s2[2]);  p0.w = __builtin_bit_cast(int, s2[3]);
    p1.x = __builtin_bit_cast(int, s2[4]);  p1.y = __builtin_bit_cast(int, s2[5]);
    p1.z = __builtin_bit_cast(int, s2[6]);  p1.w = __builtin_bit_cast(int, s2[7]);
    const f16x8 A0 = __builtin_bit_cast(f16x8, p0);
    const f16x8 A1 = __builtin_bit_cast(f16x8, p1);

    f32x4 acc[4];
#pragma unroll
    for (int c = 0; c < 4; ++c) {
      acc[c] = __builtin_amdgcn_mfma_f32_16x16x32_f16(A0, Bfrag[c][0], zero4, 0, 0, 0);
      acc[c] = __builtin_amdgcn_mfma_f32_16x16x32_f16(A1, Bfrag[c][1], acc[c], 0, 0, 0);
    }

    // sigmoid + accumulate (f32, r-pairs packed).
    // lane holds e[n = n0+quad*4+r][h2 = c*16+l15]; hrv per c via one b128.
    const f32x4 hrv4 = *(const f32x4*)&hrT[ms][l15 * 4];
#pragma unroll
    for (int c = 0; c < 4; ++c) {
      const f32x2 hrv2 = {hrv4[c], hrv4[c]};
#pragma unroll
      for (int h = 0; h < 2; ++h) {
        const f32x2 a2 = {acc[c][2 * h], acc[c][2 * h + 1]};
        const f32x2 arg = pk_fma(a2, nl2e2, b2c2[c]);
        f32x2 e2;
        e2.x = fast_exp2(arg.x);
        e2.y = fast_exp2(arg.y);
        const f32x2 dden = e2 + one2;
        f32x2 w2;
        w2.x = fast_rcp(dden.x);
        w2.y = fast_rcp(dden.y);
        numr2[c][h] = pk_fma(w2, hrv2, numr2[c][h]);
        denr2[c][h] = denr2[c][h] + w2;
      }
    }
  }

#pragma unroll
  for (int c = 0; c < 4; ++c)
#pragma unroll
    for (int h = 0; h < 2; ++h)
#pragma unroll
      for (int k = 0; k < 2; ++k) {
        const int r = 2 * h + k;
        const int n = n0 + quad * 4 + r;
        const int h2 = c * 16 + l15;
        atomicAdd(&num_g[n * 64 + h2], k ? numr2[c][h].y : numr2[c][h].x);
        atomicAdd(&den_g[n * 64 + h2], k ? denr2[c][h].y : denr2[c][h].x);
      }
}

// ---------------------------------------------------------------------------
// Node phase: one wave per row. h_agg = num/(den+1e-6); z = cat(h_l,h_agg)@Wn1
// + bn1 -> LN -> silu -> @Wn2 + bn2; out = h_l + z.
// ---------------------------------------------------------------------------
__global__ __launch_bounds__(256)
void node_kernel(const float* __restrict__ h_l,
                 const float* __restrict__ num_g,
                 const float* __restrict__ den_g,
                 const float* __restrict__ Wn1,
                 const float* __restrict__ bn1,
                 const float* __restrict__ ln_g,
                 const float* __restrict__ ln_b,
                 const float* __restrict__ Wn2,
                 const float* __restrict__ bn2,
                 float* __restrict__ out) {
  __shared__ float Wn1_s[128 * 64];
  __shared__ float Wn2_s[64 * 64];
  __shared__ float xbuf[4][128];
  __shared__ float zbuf[4][64];

  const int tid = threadIdx.x;
  for (int i = tid; i < 128 * 64; i += 256) Wn1_s[i] = Wn1[i];
  for (int i = tid; i < 64 * 64; i += 256) Wn2_s[i] = Wn2[i];

  const int wave = tid >> 6, lane = tid & 63;
  const int row = blockIdx.x * 4 + wave;

  const float hl = h_l[row * 64 + lane];
  const float dn = den_g[row * 64 + lane] + 1e-6f;
  const float hagg = num_g[row * 64 + lane] * fast_rcp(dn);
  xbuf[wave][lane] = hl;
  xbuf[wave][64 + lane] = hagg;
  __syncthreads();

  float t = bn1[lane];
#pragma unroll 8
  for (int k = 0; k < 128; ++k) t = fmaf(xbuf[wave][k], Wn1_s[k * 64 + lane], t);

  float s1 = t, s2 = t * t;
#pragma unroll
  for (int off = 32; off; off >>= 1) {
    s1 += __shfl_xor(s1, off);
    s2 += __shfl_xor(s2, off);
  }
  const float mu = s1 * 0.015625f;
  const float var = fmaf(s2, 0.015625f, -mu * mu);
  const float rs = fast_rsq(var + 1e-5f);
  const float zn = fmaf((t - mu) * rs, ln_g[lane], ln_b[lane]);
  const float sz = zn * fast_rcp(1.0f + fast_exp2(zn * NL2E));  // silu
  zbuf[wave][lane] = sz;
  __syncthreads();

  float o = bn2[lane];
#pragma unroll 8
  for (int k = 0; k < 64; ++k) o = fmaf(zbuf[wave][k], Wn2_s[k * 64 + lane], o);

  out[row * 64 + lane] = hl + o;
}

extern "C" void kernel_launch(void* const* d_in, const int* in_sizes, int n_in,
                              void* d_out, int out_size, void* d_ws, size_t ws_size,
                              hipStream_t stream) {
  const float* h_l = (const float*)d_in[0];
  const float* x_l = (const float*)d_in[1];
  const float* h_r = (const float*)d_in[2];
  const float* x_r = (const float*)d_in[3];
  const float* W1  = (const float*)d_in[4];
  const float* b1  = (const float*)d_in[5];
  const float* W2  = (const float*)d_in[6];
  const float* b2  = (const float*)d_in[7];
  const float* Wn1 = (const float*)d_in[8];
  const float* bn1 = (const float*)d_in[9];
  const float* lng = (const float*)d_in[10];
  const float* lnb = (const float*)d_in[11];
  const float* Wn2 = (const float*)d_in[12];
  const float* bn2 = (const float*)d_in[13];

  float* num_g = (float*)d_ws;
  float* den_g = num_g + (size_t)NTOT * 64;

  hipMemsetAsync(d_ws, 0, (size_t)NTOT * 64 * 2 * sizeof(float), stream);
  edge_kernel<<<dim3((NTOT / 64) * MSPLIT), dim3(256), 0, stream>>>(
      h_l, x_l, h_r, x_r, W1, b1, W2, b2, num_g, den_g);
  node_kernel<<<dim3(NTOT / 4), dim3(256), 0, stream>>>(
      h_l, num_g, den_g, Wn1, bn1, lng, lnb, Wn2, bn2, (float*)d_out);
}